// Round 7
// baseline (818.505 us; speedup 1.0000x reference)
//
#include <hip/hip_runtime.h>
#include <hip/hip_bf16.h>

#define NODES 100000
#define EDGES 1600000
#define DIM   128

typedef __bf16 bf16x8 __attribute__((ext_vector_type(8)));
typedef float  f32x4  __attribute__((ext_vector_type(4)));
typedef float  f32x2  __attribute__((ext_vector_type(2)));

// ================= edge-index dtype detection =================
// Reference declares int64; harness doc says int32. If int64 (<2^31 values),
// every odd dword of the buffer is 0. 64 random indices all-zero-odd: p~0.
__global__ void detect_kernel(const unsigned int* __restrict__ ei, int* __restrict__ flags) {
    const unsigned long long nz = __ballot(ei[2 * threadIdx.x + 1] != 0);
    if (threadIdx.x == 0) flags[0] = (nz == 0ULL) ? 1 : 0;
}

__device__ __forceinline__ int load_idx(const void* ei, long long pos, int m64) {
    return m64 ? (int)((const long long*)ei)[pos] : ((const int*)ei)[pos];
}

// ================= degree / normalization =================
__global__ __launch_bounds__(256) void zero_int_kernel(int* __restrict__ p, int n) {
    int i = blockIdx.x * 256 + threadIdx.x;
    if (i < n) p[i] = 0;
}

__global__ __launch_bounds__(256) void count_deg_kernel(const void* __restrict__ ei,
                                                        const int* __restrict__ flags,
                                                        int* __restrict__ deg, int e_cnt) {
    const int m64 = flags[0];
    int i = blockIdx.x * 256 + threadIdx.x;
    if (i < e_cnt) atomicAdd(&deg[load_idx(ei, (long long)EDGES + i, m64)], 1);
}

__global__ __launch_bounds__(256) void make_dis_kernel(const int* __restrict__ deg,
                                                       float* __restrict__ dis, int n) {
    int i = blockIdx.x * 256 + threadIdx.x;
    if (i < n) dis[i] = rsqrtf((float)deg[i] + 1.0f);
}

// ================= CSR build =================
__global__ __launch_bounds__(256) void scan1_kernel(const int* __restrict__ deg,
                                                    int* __restrict__ offs,
                                                    int* __restrict__ bsum, int n) {
    __shared__ int sm[256];
    const int t = threadIdx.x, i = blockIdx.x * 256 + t;
    const int v = (i < n) ? deg[i] : 0;
    sm[t] = v;
    __syncthreads();
    for (int d = 1; d < 256; d <<= 1) {     // Hillis-Steele inclusive scan
        const int add = (t >= d) ? sm[t - d] : 0;
        __syncthreads();
        sm[t] += add;
        __syncthreads();
    }
    if (i < n) offs[i] = sm[t] - v;         // block-local exclusive
    if (t == 255) bsum[blockIdx.x] = sm[255];
}

__global__ void scan2_kernel(const int* __restrict__ bsum, int* __restrict__ boff,
                             int* __restrict__ offs, int nb, int n) {
    if (threadIdx.x == 0) {
        int run = 0;
        for (int b = 0; b < nb; b++) { boff[b] = run; run += bsum[b]; }
        offs[n] = run;                      // == E
    }
}

__global__ __launch_bounds__(256) void scan3_kernel(int* __restrict__ offs,
                                                    const int* __restrict__ boff,
                                                    int* __restrict__ cursor, int n) {
    const int i = blockIdx.x * 256 + threadIdx.x;
    if (i < n) {
        const int o = offs[i] + boff[blockIdx.x];
        offs[i]   = o;
        cursor[i] = o;
    }
}

__global__ __launch_bounds__(256) void fill_csr_kernel(const void* __restrict__ ei,
                                                       const int* __restrict__ flags,
                                                       const float* __restrict__ dis,
                                                       int* __restrict__ cursor,
                                                       int* __restrict__ csr_src,
                                                       float* __restrict__ csr_coef,
                                                       int e_cnt) {
    const int m64 = flags[0];
    int e = blockIdx.x * 256 + threadIdx.x;
    if (e >= e_cnt) return;
    const int s = load_idx(ei, e, m64);
    const int d = load_idx(ei, (long long)EDGES + e, m64);
    const int idx = atomicAdd(&cursor[d], 1);   // int atomic: safe on any memory
    csr_src[idx]  = s;
    csr_coef[idx] = dis[s] * dis[d];
}

// ================= GEMM: fp32 [M x 128] @ fp32 [128 x 128] -> fp32 =================
// bf16 MFMA inside (B-layout V0: on-device verified r6; A/C-D layouts m89/m91-verified).
// RELU_BIAS=1: out = relu(A@W + bias)   else: out = A@W
template <int RELU_BIAS>
__global__ __launch_bounds__(256) void gemm128_kernel(
    const float* __restrict__ A, const float* __restrict__ W,
    const float* __restrict__ bias, float* __restrict__ out, int M)
{
    const int wave = threadIdx.x >> 6;
    const int lane = threadIdx.x & 63;
    const int l15  = lane & 15;
    const int quad = lane >> 4;

    // B fragments: B[k = kt*32 + quad*8 + j][n = ct*16 + l15]
    bf16x8 bfrag[8][4];
#pragma unroll
    for (int ct = 0; ct < 8; ct++)
#pragma unroll
        for (int kt = 0; kt < 4; kt++) {
            bf16x8 b;
#pragma unroll
            for (int j = 0; j < 8; j++)
                b[j] = (__bf16)W[(kt * 32 + quad * 8 + j) * DIM + ct * 16 + l15];
            bfrag[ct][kt] = b;
        }

    const int row0base = blockIdx.x * 256 + wave * 64;
#pragma unroll
    for (int rt = 0; rt < 4; rt++) {
        const int row0 = row0base + rt * 16;
        if (row0 >= M) break;  // wave-uniform

        const int arow  = row0 + l15;
        const int arowc = arow < M ? arow : (M - 1);
        // A fragment: A[m = lane&15][k = kt*32 + quad*8 + j]
        const float* ap = A + (size_t)arowc * DIM + quad * 8;
        bf16x8 afrag[4];
#pragma unroll
        for (int kt = 0; kt < 4; kt++) {
            const f32x4 lo = *(const f32x4*)(ap + kt * 32);
            const f32x4 hi = *(const f32x4*)(ap + kt * 32 + 4);
            bf16x8 r;
#pragma unroll
            for (int j = 0; j < 4; j++) { r[j] = (__bf16)lo[j]; r[j + 4] = (__bf16)hi[j]; }
            afrag[kt] = r;
        }

        f32x4 acc[8];
#pragma unroll
        for (int ct = 0; ct < 8; ct++) {
            f32x4 c = {0.f, 0.f, 0.f, 0.f};
#pragma unroll
            for (int kt = 0; kt < 4; kt++)
                c = __builtin_amdgcn_mfma_f32_16x16x32_bf16(afrag[kt], bfrag[ct][kt], c, 0, 0, 0);
            acc[ct] = c;
        }

        // C/D: row = row0 + quad*4 + r, col = ct*16 + l15
#pragma unroll
        for (int r = 0; r < 4; r++) {
            const int row = row0 + quad * 4 + r;
            if (row < M) {
#pragma unroll
                for (int ct = 0; ct < 8; ct++) {
                    float v = acc[ct][r];
                    if (RELU_BIAS) {
                        v += bias[ct * 16 + l15];
                        v = v > 0.f ? v : 0.f;
                    }
                    out[(size_t)row * DIM + ct * 16 + l15] = v;
                }
            }
        }
    }
}

// ================= aggregate (CSR gather, fp32) =================
// out[v] = act( dis[v]^2*xw[v] + sum_p coef[p]*xw[csr_src[p]] + bias )
template <int RELU>
__global__ __launch_bounds__(256) void aggregate_kernel(
    const int* __restrict__ offs, const int* __restrict__ csr_src,
    const float* __restrict__ csr_coef, const float* __restrict__ dis,
    const float* __restrict__ xw, const float* __restrict__ bias,
    float* __restrict__ out, int n)
{
    const int v = blockIdx.x * 4 + (threadIdx.x >> 6);  // one wave per node
    if (v >= n) return;
    const int lane = threadIdx.x & 63;
    const int c = lane * 2;                             // 2 feature cols per lane

    const int beg = offs[v];
    const int end = offs[v + 1];

    float a0, a1;
    {
        const float dv = dis[v];
        const f32x2 xs = *(const f32x2*)(xw + (size_t)v * DIM + c);
        a0 = dv * dv * xs[0];
        a1 = dv * dv * xs[1];
    }
    for (int p = beg; p < end; p++) {
        const int   s  = csr_src[p];
        const float cf = csr_coef[p];
        const f32x2 xv = *(const f32x2*)(xw + (size_t)s * DIM + c);
        a0 += cf * xv[0];
        a1 += cf * xv[1];
    }
    a0 += bias[c];
    a1 += bias[c + 1];
    if (RELU) { a0 = a0 > 0.f ? a0 : 0.f; a1 = a1 > 0.f ? a1 : 0.f; }
    f32x2 r; r[0] = a0; r[1] = a1;
    *(f32x2*)(out + (size_t)v * DIM + c) = r;
}

// ================= launcher =================
extern "C" void kernel_launch(void* const* d_in, const int* in_sizes, int n_in,
                              void* d_out, int out_size, void* d_ws, size_t ws_size,
                              hipStream_t stream)
{
    const int N = NODES, E = EDGES;
    const size_t ND = (size_t)N * DIM;

    const float* x  = (const float*)d_in[0];
    const void*  ei = d_in[1];   // [2,E]: src then dst (int32 or int64)
    const float* W1 = (const float*)d_in[2];
    const float* b1 = (const float*)d_in[3];
    const float* W2 = (const float*)d_in[4];
    const float* b2 = (const float*)d_in[5];
    const float* Wv = (const float*)d_in[6];
    const float* bv = (const float*)d_in[7];
    const float* Wt = (const float*)d_in[8];
    const float* bt = (const float*)d_in[9];

    // ws layout (~16.9 MB)
    char* w = (char*)d_ws;
    int*   flags    = (int*)(w);                  // 256 B
    int*   deg      = (int*)(w + (1 << 10));      // N ints
    float* dis      = (float*)(w + (512 << 10));  // N f32
    int*   offs     = (int*)(w + (1 << 20));      // N+1 ints
    int*   cursor   = (int*)(w + 1572864);        // N ints
    int*   bsum     = (int*)(w + 2097152);        // 391 ints
    int*   boff     = (int*)(w + 2101248);        // 391 ints
    int*   csr_src  = (int*)(w + 3145728);        // E ints
    float* csr_coef = (float*)(w + 10485760);     // E f32

    // fp32 out slots (ND floats each). Rotation, no reader/writer overlap:
    // xw1->slot2; h1->slot1; xw2->slot2; h->slot0; vis->slot1; txt->slot2
    float* out   = (float*)d_out;
    float* slot0 = out;
    float* slot1 = out + ND;
    float* slot2 = out + 2 * ND;

    const int GN  = (N + 255) / 256;   // 391
    const int GE  = (E + 255) / 256;
    const int GM  = (N + 255) / 256;
    const int GAG = (N + 3) / 4;       // 25000

    detect_kernel<<<1, 64, 0, stream>>>((const unsigned int*)ei, flags);
    zero_int_kernel<<<GN, 256, 0, stream>>>(deg, N);
    count_deg_kernel<<<GE, 256, 0, stream>>>(ei, flags, deg, E);
    make_dis_kernel<<<GN, 256, 0, stream>>>(deg, dis, N);

    scan1_kernel<<<GN, 256, 0, stream>>>(deg, offs, bsum, N);
    scan2_kernel<<<1, 64, 0, stream>>>(bsum, boff, offs, GN, N);
    scan3_kernel<<<GN, 256, 0, stream>>>(offs, boff, cursor, N);
    fill_csr_kernel<<<GE, 256, 0, stream>>>(ei, flags, dis, cursor, csr_src, csr_coef, E);

    // ---- layer 1 ----
    gemm128_kernel<0><<<GM, 256, 0, stream>>>(x, W1, nullptr, slot2, N);
    aggregate_kernel<1><<<GAG, 256, 0, stream>>>(offs, csr_src, csr_coef, dis, slot2, b1, slot1, N);

    // ---- layer 2 ----
    gemm128_kernel<0><<<GM, 256, 0, stream>>>(slot1, W2, nullptr, slot2, N);
    aggregate_kernel<0><<<GAG, 256, 0, stream>>>(offs, csr_src, csr_coef, dis, slot2, b2, slot0, N);

    // ---- heads ----
    gemm128_kernel<1><<<GM, 256, 0, stream>>>(slot0, Wv, bv, slot1, N);
    gemm128_kernel<1><<<GM, 256, 0, stream>>>(slot0, Wt, bt, slot2, N);
}